// Round 1
// baseline (1088.801 us; speedup 1.0000x reference)
//
#include <hip/hip_runtime.h>

typedef __bf16 bf16;
typedef __bf16 bf16x8 __attribute__((ext_vector_type(8)));
typedef float f32x4 __attribute__((ext_vector_type(4)));

#define B_SZ   4
#define S_LEN  2048
#define DM     1024
#define NH     16
#define DKH    64
#define MROWS  (B_SZ * S_LEN)   // 8192

__device__ __forceinline__ void gload_lds16(const void* g, void* l) {
  __builtin_amdgcn_global_load_lds(
      (const __attribute__((address_space(1))) void*)g,
      (__attribute__((address_space(3))) void*)l, 16, 0, 0);
}

// ---------------- fp32 -> bf16 convert (vectorized) ----------------
__global__ __launch_bounds__(256) void cvt_f32_bf16(const float* __restrict__ in,
                                                    bf16* __restrict__ out, int n8) {
  for (int i = blockIdx.x * blockDim.x + threadIdx.x; i < n8; i += gridDim.x * blockDim.x) {
    const float4* p = (const float4*)(in + (size_t)i * 8);
    float4 a = p[0], b = p[1];
    bf16x8 o;
    o[0] = (bf16)a.x; o[1] = (bf16)a.y; o[2] = (bf16)a.z; o[3] = (bf16)a.w;
    o[4] = (bf16)b.x; o[5] = (bf16)b.y; o[6] = (bf16)b.z; o[7] = (bf16)b.w;
    *(bf16x8*)(out + (size_t)i * 8) = o;
  }
}

// ---------------- GEMM: C[M,N] = A[M,K] * B[N,K]^T + bias ----------------
// MODE 0: output bf16, reorder [m=b*S+s, n=h*64+d] -> Q[b][h][s][d]
// MODE 1: output fp32 row-major [M,N]
template <int MODE>
__global__ __launch_bounds__(256) void gemm_bt(const bf16* __restrict__ A,
                                               const bf16* __restrict__ Bm,
                                               const float* __restrict__ bias,
                                               void* __restrict__ out) {
  constexpr int BM = 128, BN = 128, BK = 64, K = DM, N = DM;
  __shared__ bf16 As[BM * BK];
  __shared__ bf16 Bs[BN * BK];
  const int tid = threadIdx.x;
  const int l = tid & 63;
  const int w = tid >> 6;
  const int wr = w >> 1, wc = w & 1;
  const int m0 = (blockIdx.x >> 3) * BM;
  const int n0 = (blockIdx.x & 7) * BN;
  const int lrow = l & 15;
  const int lk = (l >> 4) * 8;

  f32x4 acc[4][4] = {};

  for (int kt = 0; kt < K; kt += BK) {
    __syncthreads();
#pragma unroll
    for (int r = 0; r < 4; ++r) {
      int c = r * 256 + tid;
      gload_lds16(A + (size_t)(m0 + (c >> 3)) * K + kt + (c & 7) * 8, As + c * 8);
      gload_lds16(Bm + (size_t)(n0 + (c >> 3)) * K + kt + (c & 7) * 8, Bs + c * 8);
    }
    __syncthreads();
#pragma unroll
    for (int kk = 0; kk < BK; kk += 32) {
      bf16x8 a[4], b[4];
#pragma unroll
      for (int i = 0; i < 4; ++i) {
        a[i] = *(const bf16x8*)(As + (wr * 64 + i * 16 + lrow) * BK + kk + lk);
        b[i] = *(const bf16x8*)(Bs + (wc * 64 + i * 16 + lrow) * BK + kk + lk);
      }
#pragma unroll
      for (int i = 0; i < 4; ++i)
#pragma unroll
        for (int j = 0; j < 4; ++j)
          acc[i][j] = __builtin_amdgcn_mfma_f32_16x16x32_bf16(a[i], b[j], acc[i][j], 0, 0, 0);
    }
  }

#pragma unroll
  for (int i = 0; i < 4; ++i) {
#pragma unroll
    for (int j = 0; j < 4; ++j) {
#pragma unroll
      for (int r = 0; r < 4; ++r) {
        int row = m0 + wr * 64 + i * 16 + (l >> 4) * 4 + r;
        int col = n0 + wc * 64 + j * 16 + (l & 15);
        float v = acc[i][j][r] + bias[col];
        if (MODE == 0) {
          int bb = row >> 11, ss = row & 2047, hh = col >> 6, dd = col & 63;
          ((bf16*)out)[(((size_t)bb * NH + hh) * S_LEN + ss) * DKH + dd] = (bf16)v;
        } else {
          ((float*)out)[(size_t)row * N + col] = v;
        }
      }
    }
  }
}

// ---------------- fused attention ----------------
// Q,K,V: [B*H, S, 64] bf16. attn: [B*H, S, S] fp32. ctx: [B, S, DM] bf16.
__device__ __forceinline__ void qk_tile(const bf16* __restrict__ Qs,
                                        const bf16* __restrict__ Ks,
                                        int w, int lrow, int lk, f32x4 s[2][4]) {
#pragma unroll
  for (int kk = 0; kk < DKH; kk += 32) {
    bf16x8 a0 = *(const bf16x8*)(Qs + (w * 32 + lrow) * DKH + kk + lk);
    bf16x8 a1 = *(const bf16x8*)(Qs + (w * 32 + 16 + lrow) * DKH + kk + lk);
#pragma unroll
    for (int n = 0; n < 4; ++n) {
      bf16x8 b = *(const bf16x8*)(Ks + (n * 16 + lrow) * DKH + kk + lk);
      s[0][n] = __builtin_amdgcn_mfma_f32_16x16x32_bf16(a0, b, s[0][n], 0, 0, 0);
      s[1][n] = __builtin_amdgcn_mfma_f32_16x16x32_bf16(a1, b, s[1][n], 0, 0, 0);
    }
  }
}

__global__ __launch_bounds__(256) void attn_fused(const bf16* __restrict__ Q,
                                                  const bf16* __restrict__ Kg,
                                                  const bf16* __restrict__ Vg,
                                                  float* __restrict__ attn,
                                                  bf16* __restrict__ ctx) {
  constexpr int QT = 128, KT = 64, PSS = 68;
  __shared__ bf16 Qs[QT * DKH];     // 16 KB
  __shared__ bf16 Ks[KT * DKH];     // 8 KB
  __shared__ bf16 Vts[DKH * KT];    // 8 KB (transposed V: [d][kv])
  __shared__ float Ps[QT * PSS];    // 34 KB

  const int tid = threadIdx.x, l = tid & 63, w = tid >> 6;
  const int bh = blockIdx.x >> 4;
  const int q0 = (blockIdx.x & 15) * QT;
  const bf16* Qb = Q + (size_t)bh * S_LEN * DKH;
  const bf16* Kb = Kg + (size_t)bh * S_LEN * DKH;
  const bf16* Vb = Vg + (size_t)bh * S_LEN * DKH;
  const int lrow = l & 15, lk = (l >> 4) * 8;
  const float scale = 0.125f;  // 1/sqrt(64)

  // stage Q once
#pragma unroll
  for (int r = 0; r < 4; ++r) {
    int c = r * 256 + tid;
    gload_lds16(Qb + (size_t)(q0 + (c >> 3)) * DKH + (c & 7) * 8, Qs + c * 8);
  }

  float mrun[2][4], lrun[2][4];
#pragma unroll
  for (int m = 0; m < 2; ++m)
#pragma unroll
    for (int r = 0; r < 4; ++r) { mrun[m][r] = -1e30f; lrun[m][r] = 0.f; }

  // ---- pass 1: online max/sum ----
  for (int kt = 0; kt < S_LEN; kt += KT) {
    __syncthreads();
#pragma unroll
    for (int r = 0; r < 2; ++r) {
      int c = r * 256 + tid;
      gload_lds16(Kb + (size_t)(kt + (c >> 3)) * DKH + (c & 7) * 8, Ks + c * 8);
    }
    __syncthreads();
    f32x4 s[2][4] = {};
    qk_tile(Qs, Ks, w, lrow, lk, s);
#pragma unroll
    for (int m = 0; m < 2; ++m) {
#pragma unroll
      for (int r = 0; r < 4; ++r) {
        float v0 = s[m][0][r] * scale, v1 = s[m][1][r] * scale;
        float v2 = s[m][2][r] * scale, v3 = s[m][3][r] * scale;
        float tm = fmaxf(fmaxf(v0, v1), fmaxf(v2, v3));
#pragma unroll
        for (int d = 1; d < 16; d <<= 1) tm = fmaxf(tm, __shfl_xor(tm, d));
        float nm = fmaxf(mrun[m][r], tm);
        float ts = expf(v0 - nm) + expf(v1 - nm) + expf(v2 - nm) + expf(v3 - nm);
#pragma unroll
        for (int d = 1; d < 16; d <<= 1) ts += __shfl_xor(ts, d);
        lrun[m][r] = lrun[m][r] * expf(mrun[m][r] - nm) + ts;
        mrun[m][r] = nm;
      }
    }
  }

  float invl[2][4];
#pragma unroll
  for (int m = 0; m < 2; ++m)
#pragma unroll
    for (int r = 0; r < 4; ++r) invl[m][r] = 1.0f / lrun[m][r];

  // ---- pass 2: recompute, write attn, accumulate ctx ----
  f32x4 oc[2][4] = {};
  for (int kt = 0; kt < S_LEN; kt += KT) {
    __syncthreads();
#pragma unroll
    for (int r = 0; r < 2; ++r) {
      int c = r * 256 + tid;
      gload_lds16(Kb + (size_t)(kt + (c >> 3)) * DKH + (c & 7) * 8, Ks + c * 8);
    }
    // stage V transposed (reg-staged)
#pragma unroll
    for (int r = 0; r < 2; ++r) {
      int c = r * 256 + tid;
      int kv = c >> 3, d0 = (c & 7) * 8;
      bf16x8 vv = *(const bf16x8*)(Vb + (size_t)(kt + kv) * DKH + d0);
#pragma unroll
      for (int j = 0; j < 8; ++j) Vts[(d0 + j) * KT + kv] = vv[j];
    }
    __syncthreads();
    f32x4 s[2][4] = {};
    qk_tile(Qs, Ks, w, lrow, lk, s);
#pragma unroll
    for (int m = 0; m < 2; ++m)
#pragma unroll
      for (int n = 0; n < 4; ++n)
#pragma unroll
        for (int r = 0; r < 4; ++r) {
          float p = expf(s[m][n][r] * scale - mrun[m][r]) * invl[m][r];
          Ps[(w * 32 + m * 16 + (l >> 4) * 4 + r) * PSS + n * 16 + (l & 15)] = p;
        }
    __syncthreads();
    // coalesced attn write (float4)
    float* arow = attn + (size_t)bh * S_LEN * S_LEN + (size_t)q0 * S_LEN + kt;
#pragma unroll
    for (int it = 0; it < 8; ++it) {
      int idx = it * 256 + tid;
      int row = idx >> 4, c4 = (idx & 15) * 4;
      *(float4*)(arow + (size_t)row * S_LEN + c4) = *(const float4*)(Ps + row * PSS + c4);
    }
    // PV accumulate
#pragma unroll
    for (int kk = 0; kk < KT; kk += 32) {
      bf16x8 b[4];
#pragma unroll
      for (int n = 0; n < 4; ++n)
        b[n] = *(const bf16x8*)(Vts + (n * 16 + lrow) * KT + kk + lk);
#pragma unroll
      for (int m = 0; m < 2; ++m) {
        const float* pf = Ps + (w * 32 + m * 16 + lrow) * PSS + kk + lk;
        f32x4 p0 = *(const f32x4*)(pf);
        f32x4 p1 = *(const f32x4*)(pf + 4);
        bf16x8 pa;
#pragma unroll
        for (int j = 0; j < 4; ++j) { pa[j] = (bf16)p0[j]; pa[j + 4] = (bf16)p1[j]; }
#pragma unroll
        for (int n = 0; n < 4; ++n)
          oc[m][n] = __builtin_amdgcn_mfma_f32_16x16x32_bf16(pa, b[n], oc[m][n], 0, 0, 0);
      }
    }
  }

  // ctx epilogue: [B, S, DM] bf16
  const int bb = bh >> 4, hh = bh & 15;
#pragma unroll
  for (int m = 0; m < 2; ++m)
#pragma unroll
    for (int n = 0; n < 4; ++n)
#pragma unroll
      for (int r = 0; r < 4; ++r) {
        int row = q0 + w * 32 + m * 16 + (l >> 4) * 4 + r;
        int col = hh * DKH + n * 16 + (l & 15);
        ctx[((size_t)bb * S_LEN + row) * DM + col] = (bf16)oc[m][n][r];
      }
}

extern "C" void kernel_launch(void* const* d_in, const int* in_sizes, int n_in,
                              void* d_out, int out_size, void* d_ws, size_t ws_size,
                              hipStream_t stream) {
  const float* query = (const float*)d_in[0];
  const float* key_i = (const float*)d_in[1];
  const float* value = (const float*)d_in[2];
  const float* w_q = (const float*)d_in[3];
  const float* b_q = (const float*)d_in[4];
  const float* w_k = (const float*)d_in[5];
  const float* b_k = (const float*)d_in[6];
  const float* w_v = (const float*)d_in[7];
  const float* b_v = (const float*)d_in[8];
  const float* w_o = (const float*)d_in[9];
  const float* b_o = (const float*)d_in[10];

  // workspace layout (bf16 buffers), total 82 MB
  char* ws = (char*)d_ws;
  bf16* Xb = (bf16*)(ws);                          // 16 MB  (X converted)
  bf16* Wb = (bf16*)(ws + ((size_t)16 << 20));     // 2 MB   (W converted)
  bf16* Qb = (bf16*)(ws + ((size_t)18 << 20));     // 16 MB  [B*H,S,64]
  bf16* Kb = (bf16*)(ws + ((size_t)34 << 20));     // 16 MB
  bf16* Vb = (bf16*)(ws + ((size_t)50 << 20));     // 16 MB
  bf16* Cb = (bf16*)(ws + ((size_t)66 << 20));     // 16 MB  ctx [B,S,DM]

  float* outp = (float*)d_out;
  float* attnp = outp + (size_t)B_SZ * S_LEN * DM;

  const int NX = MROWS * DM / 8;  // 1,048,576
  const int NW = DM * DM / 8;     // 131,072
  dim3 blk(256);

  // Q projection
  cvt_f32_bf16<<<2048, blk, 0, stream>>>(query, Xb, NX);
  cvt_f32_bf16<<<512, blk, 0, stream>>>(w_q, Wb, NW);
  gemm_bt<0><<<512, blk, 0, stream>>>(Xb, Wb, b_q, Qb);
  // K projection
  cvt_f32_bf16<<<2048, blk, 0, stream>>>(key_i, Xb, NX);
  cvt_f32_bf16<<<512, blk, 0, stream>>>(w_k, Wb, NW);
  gemm_bt<0><<<512, blk, 0, stream>>>(Xb, Wb, b_k, Kb);
  // V projection
  cvt_f32_bf16<<<2048, blk, 0, stream>>>(value, Xb, NX);
  cvt_f32_bf16<<<512, blk, 0, stream>>>(w_v, Wb, NW);
  gemm_bt<0><<<512, blk, 0, stream>>>(Xb, Wb, b_v, Vb);

  // fused attention: writes attn (fp32) + ctx (bf16)
  attn_fused<<<B_SZ * NH * (S_LEN / 128), blk, 0, stream>>>(Qb, Kb, Vb, attnp, Cb);

  // output projection
  cvt_f32_bf16<<<512, blk, 0, stream>>>(w_o, Wb, NW);
  gemm_bt<1><<<512, blk, 0, stream>>>(Cb, Wb, b_o, (void*)outp);
}

// Round 2
// 542.216 us; speedup vs baseline: 2.0081x; 2.0081x over previous
//
#include <hip/hip_runtime.h>

typedef __bf16 bf16;
typedef __bf16 bf16x8 __attribute__((ext_vector_type(8)));
typedef float f32x4 __attribute__((ext_vector_type(4)));

#define B_SZ   4
#define S_LEN  2048
#define DM     1024
#define NH     16
#define DKH    64
#define MROWS  (B_SZ * S_LEN)   // 8192

#if __has_builtin(__builtin_amdgcn_exp2f)
#define EXP2(x) __builtin_amdgcn_exp2f(x)
#else
#define EXP2(x) exp2f(x)
#endif

// XOR swizzle: applies to the byte offset within a 128-B row; conflict-free for
// 16-lane row-varying b128 reads AND for the V-transpose scalar write pattern.
__device__ __forceinline__ int swz_(int row) { return ((row ^ (row >> 3)) & 7) << 4; }

__device__ __forceinline__ void gload_lds16(const void* g, void* l) {
  __builtin_amdgcn_global_load_lds(
      (const __attribute__((address_space(1))) void*)g,
      (__attribute__((address_space(3))) void*)l, 16, 0, 0);
}

// ---------------- fp32 -> bf16 convert (vectorized) ----------------
__global__ __launch_bounds__(256) void cvt_f32_bf16(const float* __restrict__ in,
                                                    bf16* __restrict__ out, int n8) {
  for (int i = blockIdx.x * blockDim.x + threadIdx.x; i < n8; i += gridDim.x * blockDim.x) {
    const float4* p = (const float4*)(in + (size_t)i * 8);
    float4 a = p[0], b = p[1];
    bf16x8 o;
    o[0] = (bf16)a.x; o[1] = (bf16)a.y; o[2] = (bf16)a.z; o[3] = (bf16)a.w;
    o[4] = (bf16)b.x; o[5] = (bf16)b.y; o[6] = (bf16)b.z; o[7] = (bf16)b.w;
    *(bf16x8*)(out + (size_t)i * 8) = o;
  }
}

// ---------------- GEMM: C[M,N] = A[M,K] * B[N,K]^T + bias ----------------
template <int MODE>
__global__ __launch_bounds__(256) void gemm_bt(const bf16* __restrict__ A,
                                               const bf16* __restrict__ Bm,
                                               const float* __restrict__ bias,
                                               void* __restrict__ out) {
  constexpr int BM = 128, BN = 128, BK = 64, K = DM, N = DM;
  __shared__ bf16 As[BM * BK];
  __shared__ bf16 Bs[BN * BK];
  const int tid = threadIdx.x;
  const int l = tid & 63;
  const int w = tid >> 6;
  const int wr = w >> 1, wc = w & 1;
  const int m0 = (blockIdx.x >> 3) * BM;
  const int n0 = (blockIdx.x & 7) * BN;
  const int lrow = l & 15;
  const int lk = (l >> 4) * 8;

  f32x4 acc[4][4] = {};

  for (int kt = 0; kt < K; kt += BK) {
    __syncthreads();
#pragma unroll
    for (int r = 0; r < 4; ++r) {
      int c = r * 256 + tid;
      int row = c >> 3;
      int cb = ((c & 7) * 16) ^ swz_(row);   // pre-swizzled source byte offset
      gload_lds16((const char*)(A + (size_t)(m0 + row) * K + kt) + cb, (char*)As + c * 16);
      gload_lds16((const char*)(Bm + (size_t)(n0 + row) * K + kt) + cb, (char*)Bs + c * 16);
    }
    __syncthreads();
#pragma unroll
    for (int kk = 0; kk < BK; kk += 32) {
      bf16x8 a[4], b[4];
#pragma unroll
      for (int i = 0; i < 4; ++i) {
        int ar = wr * 64 + i * 16 + lrow;
        int br = wc * 64 + i * 16 + lrow;
        a[i] = *(const bf16x8*)((const char*)As + ar * 128 + (((kk + lk) * 2) ^ swz_(ar)));
        b[i] = *(const bf16x8*)((const char*)Bs + br * 128 + (((kk + lk) * 2) ^ swz_(br)));
      }
#pragma unroll
      for (int i = 0; i < 4; ++i)
#pragma unroll
        for (int j = 0; j < 4; ++j)
          acc[i][j] = __builtin_amdgcn_mfma_f32_16x16x32_bf16(a[i], b[j], acc[i][j], 0, 0, 0);
    }
  }

#pragma unroll
  for (int i = 0; i < 4; ++i) {
#pragma unroll
    for (int j = 0; j < 4; ++j) {
#pragma unroll
      for (int r = 0; r < 4; ++r) {
        int row = m0 + wr * 64 + i * 16 + (l >> 4) * 4 + r;
        int col = n0 + wc * 64 + j * 16 + (l & 15);
        float v = acc[i][j][r] + bias[col];
        if (MODE == 0) {
          int bb = row >> 11, ss = row & 2047, hh = col >> 6, dd = col & 63;
          ((bf16*)out)[(((size_t)bb * NH + hh) * S_LEN + ss) * DKH + dd] = (bf16)v;
        } else {
          ((float*)out)[(size_t)row * N + col] = v;
        }
      }
    }
  }
}

// ---------------- fused attention ----------------
// Q,K,V: [B*H, S, 64] bf16 (LDS copies XOR-swizzled). attn fp32, ctx bf16.
__device__ __forceinline__ void qk_tile(const bf16* __restrict__ Qs,
                                        const bf16* __restrict__ Ks,
                                        int w, int lrow, int lk, f32x4 s[2][4]) {
#pragma unroll
  for (int kk = 0; kk < DKH; kk += 32) {
    int qr0 = w * 32 + lrow, qr1 = w * 32 + 16 + lrow;
    bf16x8 a0 = *(const bf16x8*)((const char*)Qs + qr0 * 128 + (((kk + lk) * 2) ^ swz_(qr0)));
    bf16x8 a1 = *(const bf16x8*)((const char*)Qs + qr1 * 128 + (((kk + lk) * 2) ^ swz_(qr1)));
#pragma unroll
    for (int n = 0; n < 4; ++n) {
      int kr = n * 16 + lrow;
      bf16x8 b = *(const bf16x8*)((const char*)Ks + kr * 128 + (((kk + lk) * 2) ^ swz_(kr)));
      s[0][n] = __builtin_amdgcn_mfma_f32_16x16x32_bf16(a0, b, s[0][n], 0, 0, 0);
      s[1][n] = __builtin_amdgcn_mfma_f32_16x16x32_bf16(a1, b, s[1][n], 0, 0, 0);
    }
  }
}

__global__ __launch_bounds__(256, 3) void attn_fused(const bf16* __restrict__ Q,
                                                     const bf16* __restrict__ Kg,
                                                     const bf16* __restrict__ Vg,
                                                     float* __restrict__ attn,
                                                     bf16* __restrict__ ctx) {
  constexpr int QT = 128, KT = 64, PSP = 72;
  __shared__ bf16 Qs[QT * DKH];     // 16 KB (swizzled)
  __shared__ bf16 Ks[KT * DKH];     // 8 KB  (swizzled)
  __shared__ bf16 Vts[DKH * KT];    // 8 KB  (transposed [d][kv], swizzled)
  __shared__ bf16 Ps[QT * PSP];     // 18 KB (bf16 P for PV)

  const int tid = threadIdx.x, l = tid & 63, w = tid >> 6;
  const int bh = blockIdx.x >> 4;
  const int q0 = (blockIdx.x & 15) * QT;
  const bf16* Qb = Q + (size_t)bh * S_LEN * DKH;
  const bf16* Kb = Kg + (size_t)bh * S_LEN * DKH;
  const bf16* Vb = Vg + (size_t)bh * S_LEN * DKH;
  const int lrow = l & 15, lk = (l >> 4) * 8;
  const float c2 = 0.18033688011f;  // (1/8) * log2(e)

  // stage Q once (pre-swizzled source -> linear LDS == swizzled layout)
#pragma unroll
  for (int r = 0; r < 4; ++r) {
    int c = r * 256 + tid;
    int row = c >> 3;
    int cb = ((c & 7) * 16) ^ swz_(row);
    gload_lds16((const char*)(Qb + (size_t)(q0 + row) * DKH) + cb, (char*)Qs + c * 16);
  }

  float mrun[2][4], lsum[2][4];
#pragma unroll
  for (int m = 0; m < 2; ++m)
#pragma unroll
    for (int r = 0; r < 4; ++r) { mrun[m][r] = -1e30f; lsum[m][r] = 0.f; }

  // ---- pass 1: per-lane online max/sum (no cross-lane work per tile) ----
  for (int kt = 0; kt < S_LEN; kt += KT) {
    __syncthreads();
#pragma unroll
    for (int r = 0; r < 2; ++r) {
      int c = r * 256 + tid;
      int row = c >> 3;
      int cb = ((c & 7) * 16) ^ swz_(row);
      gload_lds16((const char*)(Kb + (size_t)(kt + row) * DKH) + cb, (char*)Ks + c * 16);
    }
    __syncthreads();
    f32x4 s[2][4] = {};
    qk_tile(Qs, Ks, w, lrow, lk, s);
#pragma unroll
    for (int m = 0; m < 2; ++m) {
#pragma unroll
      for (int r = 0; r < 4; ++r) {
        float v0 = s[m][0][r] * c2, v1 = s[m][1][r] * c2;
        float v2 = s[m][2][r] * c2, v3 = s[m][3][r] * c2;
        float tm = fmaxf(fmaxf(v0, v1), fmaxf(v2, v3));
        float nm = fmaxf(mrun[m][r], tm);
        float sc = EXP2(mrun[m][r] - nm);
        lsum[m][r] = lsum[m][r] * sc +
                     EXP2(v0 - nm) + EXP2(v1 - nm) + EXP2(v2 - nm) + EXP2(v3 - nm);
        mrun[m][r] = nm;
      }
    }
  }

  // end-of-pass-1 cross-lane merge (4 butterfly steps within 16-lane group)
  float invl[2][4];
#pragma unroll
  for (int m = 0; m < 2; ++m)
#pragma unroll
    for (int r = 0; r < 4; ++r) {
      float mm = mrun[m][r], ll = lsum[m][r];
#pragma unroll
      for (int d = 1; d < 16; d <<= 1) {
        float mo = __shfl_xor(mm, d);
        float lo = __shfl_xor(ll, d);
        float nm = fmaxf(mm, mo);
        ll = ll * EXP2(mm - nm) + lo * EXP2(mo - nm);
        mm = nm;
      }
      mrun[m][r] = mm;
      invl[m][r] = 1.0f / ll;
    }

  // per-lane attn output base: row = q0 + w*32 + (l>>4)*4, col = (l&15)
  const size_t abase = (size_t)bh * S_LEN * S_LEN +
                       (size_t)(q0 + w * 32 + (l >> 4) * 4) * S_LEN + (l & 15);

  // ---- pass 2: recompute, write attn from regs, bf16 P -> LDS, PV ----
  f32x4 oc[2][4] = {};
  for (int kt = 0; kt < S_LEN; kt += KT) {
    __syncthreads();
#pragma unroll
    for (int r = 0; r < 2; ++r) {
      int c = r * 256 + tid;
      int row = c >> 3;
      int cb = ((c & 7) * 16) ^ swz_(row);
      gload_lds16((const char*)(Kb + (size_t)(kt + row) * DKH) + cb, (char*)Ks + c * 16);
    }
    // stage V transposed with swizzled scalar writes (conflict-free both sides)
#pragma unroll
    for (int r = 0; r < 2; ++r) {
      int c = r * 256 + tid;
      int kv = c >> 3, d0 = (c & 7) * 8;
      bf16x8 vv = *(const bf16x8*)(Vb + (size_t)(kt + kv) * DKH + d0);
#pragma unroll
      for (int j = 0; j < 8; ++j) {
        int row = d0 + j;
        *(bf16*)((char*)Vts + row * 128 + ((kv * 2) ^ swz_(row))) = vv[j];
      }
    }
    __syncthreads();
    f32x4 s[2][4] = {};
    qk_tile(Qs, Ks, w, lrow, lk, s);
#pragma unroll
    for (int m = 0; m < 2; ++m)
#pragma unroll
      for (int n = 0; n < 4; ++n)
#pragma unroll
        for (int r = 0; r < 4; ++r) {
          float p = EXP2(s[m][n][r] * c2 - mrun[m][r]) * invl[m][r];
          attn[abase + (size_t)(m * 16 + r) * S_LEN + kt + n * 16] = p;
          Ps[(w * 32 + m * 16 + (l >> 4) * 4 + r) * PSP + n * 16 + (l & 15)] = (bf16)p;
        }
    __syncthreads();
    // PV accumulate
#pragma unroll
    for (int kk = 0; kk < KT; kk += 32) {
      bf16x8 b[4];
#pragma unroll
      for (int n = 0; n < 4; ++n) {
        int vr = n * 16 + lrow;
        b[n] = *(const bf16x8*)((const char*)Vts + vr * 128 + (((kk + lk) * 2) ^ swz_(vr)));
      }
#pragma unroll
      for (int m = 0; m < 2; ++m) {
        bf16x8 pa = *(const bf16x8*)(Ps + (w * 32 + m * 16 + lrow) * PSP + kk + lk);
#pragma unroll
        for (int n = 0; n < 4; ++n)
          oc[m][n] = __builtin_amdgcn_mfma_f32_16x16x32_bf16(pa, b[n], oc[m][n], 0, 0, 0);
      }
    }
  }

  // ctx epilogue: [B, S, DM] bf16
  const int bb = bh >> 4, hh = bh & 15;
#pragma unroll
  for (int m = 0; m < 2; ++m)
#pragma unroll
    for (int n = 0; n < 4; ++n)
#pragma unroll
      for (int r = 0; r < 4; ++r) {
        int row = q0 + w * 32 + m * 16 + (l >> 4) * 4 + r;
        int col = hh * DKH + n * 16 + (l & 15);
        ctx[((size_t)bb * S_LEN + row) * DM + col] = (bf16)oc[m][n][r];
      }
}

extern "C" void kernel_launch(void* const* d_in, const int* in_sizes, int n_in,
                              void* d_out, int out_size, void* d_ws, size_t ws_size,
                              hipStream_t stream) {
  const float* query = (const float*)d_in[0];
  const float* key_i = (const float*)d_in[1];
  const float* value = (const float*)d_in[2];
  const float* w_q = (const float*)d_in[3];
  const float* b_q = (const float*)d_in[4];
  const float* w_k = (const float*)d_in[5];
  const float* b_k = (const float*)d_in[6];
  const float* w_v = (const float*)d_in[7];
  const float* b_v = (const float*)d_in[8];
  const float* w_o = (const float*)d_in[9];
  const float* b_o = (const float*)d_in[10];

  char* ws = (char*)d_ws;
  bf16* Xb = (bf16*)(ws);                          // 16 MB
  bf16* Wb = (bf16*)(ws + ((size_t)16 << 20));     // 2 MB
  bf16* Qb = (bf16*)(ws + ((size_t)18 << 20));     // 16 MB
  bf16* Kb = (bf16*)(ws + ((size_t)34 << 20));     // 16 MB
  bf16* Vb = (bf16*)(ws + ((size_t)50 << 20));     // 16 MB
  bf16* Cb = (bf16*)(ws + ((size_t)66 << 20));     // 16 MB

  float* outp = (float*)d_out;
  float* attnp = outp + (size_t)B_SZ * S_LEN * DM;

  const int NX = MROWS * DM / 8;
  const int NW = DM * DM / 8;
  dim3 blk(256);

  cvt_f32_bf16<<<2048, blk, 0, stream>>>(query, Xb, NX);
  cvt_f32_bf16<<<512, blk, 0, stream>>>(w_q, Wb, NW);
  gemm_bt<0><<<512, blk, 0, stream>>>(Xb, Wb, b_q, Qb);
  cvt_f32_bf16<<<2048, blk, 0, stream>>>(key_i, Xb, NX);
  cvt_f32_bf16<<<512, blk, 0, stream>>>(w_k, Wb, NW);
  gemm_bt<0><<<512, blk, 0, stream>>>(Xb, Wb, b_k, Kb);
  cvt_f32_bf16<<<2048, blk, 0, stream>>>(value, Xb, NX);
  cvt_f32_bf16<<<512, blk, 0, stream>>>(w_v, Wb, NW);
  gemm_bt<0><<<512, blk, 0, stream>>>(Xb, Wb, b_v, Vb);

  attn_fused<<<B_SZ * NH * (S_LEN / 128), blk, 0, stream>>>(Qb, Kb, Vb, attnp, Cb);

  cvt_f32_bf16<<<512, blk, 0, stream>>>(w_o, Wb, NW);
  gemm_bt<1><<<512, blk, 0, stream>>>(Cb, Wb, b_o, (void*)outp);
}